// Round 1
// baseline (301.841 us; speedup 1.0000x reference)
//
#include <hip/hip_runtime.h>

// Problem constants (from setup_inputs): x (64,256,56,56) f32, fc_w (32,128), fc_b (32),
// weight (1,256,1,1), bias (1,256,1,1), group=32.
constexpr int N_  = 64;
constexpr int C_  = 256;
constexpr int HW_ = 56 * 56;        // 3136, divisible by 4; slice = 12544 B (16B aligned)
constexpr int G_  = 32;
constexpr int NC_ = N_ * C_;        // 16384
constexpr float EPS_ = 1e-5f;

// ---------------- Kernel 1: per-(n,c) sum and sum-of-squares ----------------
__global__ __launch_bounds__(256) void k_sums(const float* __restrict__ x,
                                              float* __restrict__ s1,
                                              float* __restrict__ s2) {
    const int nc = blockIdx.x;
    const float4* xp = reinterpret_cast<const float4*>(x + (size_t)nc * HW_);
    constexpr int NV = HW_ / 4;     // 784
    float a = 0.f, b = 0.f;
    for (int i = threadIdx.x; i < NV; i += 256) {
        float4 v = xp[i];
        a += v.x + v.y + v.z + v.w;
        b += v.x * v.x + v.y * v.y + v.z * v.z + v.w * v.w;
    }
    // wave-64 butterfly, then cross-wave via LDS
    for (int off = 32; off; off >>= 1) {
        a += __shfl_down(a, off, 64);
        b += __shfl_down(b, off, 64);
    }
    __shared__ float sa[4], sb[4];
    const int wid = threadIdx.x >> 6, lane = threadIdx.x & 63;
    if (lane == 0) { sa[wid] = a; sb[wid] = b; }
    __syncthreads();
    if (threadIdx.x == 0) {
        s1[nc] = sa[0] + sa[1] + sa[2] + sa[3];
        s2[nc] = sb[0] + sb[1] + sb[2] + sb[3];
    }
}

// ---------------- Kernel 2: logits -> argmax -> group stats -> scale/shift ----------------
__global__ __launch_bounds__(1024) void k_stats(const float* __restrict__ s1,
                                                const float* __restrict__ s2,
                                                const float* __restrict__ fc_w,
                                                const float* __restrict__ fc_b,
                                                const float* __restrict__ weight,
                                                const float* __restrict__ bias,
                                                float* __restrict__ scale,
                                                float* __restrict__ shift) {
    __shared__ float logits[C_][G_];     // 32 KiB
    __shared__ int   gidx[C_];
    __shared__ float Sg1[N_][G_];        // 8 KiB
    __shared__ float Sg2[N_][G_];        // 8 KiB
    __shared__ int   cntc[G_];

    const float inv_hw  = 1.f / (float)HW_;
    const float inv_hw1 = 1.f / (float)(HW_ - 1);
    const int t = threadIdx.x;

    if (t < G_) cntc[t] = 0;

    // Phase A: logits[c][g] = fc_b[g] + sum_n mean_cn[c][n]*W[g][n] + var_cn[c][n]*W[g][N+n]
    for (int p = t; p < C_ * G_; p += 1024) {
        const int c = p >> 5;            // p / G_
        const int g = p & (G_ - 1);
        const float* wg = fc_w + g * (2 * N_);
        float acc = fc_b[g];
        for (int n = 0; n < N_; ++n) {
            const float v1 = s1[n * C_ + c];
            const float v2 = s2[n * C_ + c];
            const float m  = v1 * inv_hw;
            const float vr = (v2 - v1 * m) * inv_hw1;   // ddof=1
            acc += m * wg[n] + vr * wg[N_ + n];
        }
        logits[c][g] = acc;
    }
    __syncthreads();

    // Phase B: first-occurrence argmax over g (matches jnp.argmax)
    if (t < C_) {
        float best = logits[t][0];
        int bi = 0;
        for (int g = 1; g < G_; ++g) {
            const float v = logits[t][g];
            if (v > best) { best = v; bi = g; }
        }
        gidx[t] = bi;
        atomicAdd(&cntc[bi], 1);
    }
    __syncthreads();

    // Phase C: per-(n,g) group sums
    for (int p = t; p < N_ * G_; p += 1024) {
        const int n = p >> 5;
        const int g = p & (G_ - 1);
        float A = 0.f, B = 0.f;
        for (int c = 0; c < C_; ++c) {
            if (gidx[c] == g) { A += s1[n * C_ + c]; B += s2[n * C_ + c]; }
        }
        Sg1[n][g] = A;
        Sg2[n][g] = B;
    }
    __syncthreads();

    // Phase D: per-(n,c) fused scale/shift:  out = x*scale + shift
    for (int p = t; p < NC_; p += 1024) {
        const int n = p >> 8;            // p / C_
        const int c = p & (C_ - 1);
        const int g = gidx[c];
        const float cnt = (float)cntc[g] * (float)HW_;
        const float A = Sg1[n][g];
        const float m = A / fmaxf(cnt, 1.f);
        const float vr = (Sg2[n][g] - A * m) / fmaxf(cnt - 1.f, 1.f);
        const float inv = rsqrtf(vr + EPS_);
        const float sc = inv * weight[c];
        scale[p] = sc;
        shift[p] = bias[c] - m * sc;
    }
}

// ---------------- Kernel 3: elementwise normalize ----------------
__global__ __launch_bounds__(256) void k_norm(const float* __restrict__ x,
                                              const float* __restrict__ scale,
                                              const float* __restrict__ shift,
                                              float* __restrict__ out) {
    const int nc = blockIdx.x;
    const float sc = scale[nc];
    const float sh = shift[nc];
    const float4* xp = reinterpret_cast<const float4*>(x + (size_t)nc * HW_);
    float4* op = reinterpret_cast<float4*>(out + (size_t)nc * HW_);
    constexpr int NV = HW_ / 4;
    for (int i = threadIdx.x; i < NV; i += 256) {
        float4 v = xp[i];
        v.x = v.x * sc + sh;
        v.y = v.y * sc + sh;
        v.z = v.z * sc + sh;
        v.w = v.w * sc + sh;
        op[i] = v;
    }
}

extern "C" void kernel_launch(void* const* d_in, const int* in_sizes, int n_in,
                              void* d_out, int out_size, void* d_ws, size_t ws_size,
                              hipStream_t stream) {
    const float* x      = (const float*)d_in[0];
    const float* fc_w   = (const float*)d_in[1];
    const float* fc_b   = (const float*)d_in[2];
    const float* weight = (const float*)d_in[3];
    const float* bias   = (const float*)d_in[4];
    float* out = (float*)d_out;

    float* ws    = (float*)d_ws;
    float* s1    = ws;
    float* s2    = ws + NC_;
    float* scale = ws + 2 * NC_;
    float* shift = ws + 3 * NC_;

    k_sums<<<NC_, 256, 0, stream>>>(x, s1, s2);
    k_stats<<<1, 1024, 0, stream>>>(s1, s2, fc_w, fc_b, weight, bias, scale, shift);
    k_norm<<<NC_, 256, 0, stream>>>(x, scale, shift, out);
}

// Round 2
// 133.725 us; speedup vs baseline: 2.2572x; 2.2572x over previous
//
#include <hip/hip_runtime.h>

constexpr int N_  = 64;
constexpr int C_  = 256;
constexpr int HW_ = 56 * 56;        // 3136
constexpr int G_  = 32;
constexpr int NC_ = N_ * C_;        // 16384
constexpr float EPS_ = 1e-5f;

// ---------------- Kernel 1: per-(n,c) sum and sum-of-squares ----------------
__global__ __launch_bounds__(256) void k_sums(const float* __restrict__ x,
                                              float* __restrict__ s1,
                                              float* __restrict__ s2) {
    const int nc = blockIdx.x;
    const float4* xp = reinterpret_cast<const float4*>(x + (size_t)nc * HW_);
    constexpr int NV = HW_ / 4;     // 784
    float a = 0.f, b = 0.f;
    for (int i = threadIdx.x; i < NV; i += 256) {
        float4 v = xp[i];
        a += v.x + v.y + v.z + v.w;
        b += v.x * v.x + v.y * v.y + v.z * v.z + v.w * v.w;
    }
    for (int off = 32; off; off >>= 1) {
        a += __shfl_down(a, off, 64);
        b += __shfl_down(b, off, 64);
    }
    __shared__ float sa[4], sb[4];
    const int wid = threadIdx.x >> 6, lane = threadIdx.x & 63;
    if (lane == 0) { sa[wid] = a; sb[wid] = b; }
    __syncthreads();
    if (threadIdx.x == 0) {
        s1[nc] = sa[0] + sa[1] + sa[2] + sa[3];
        s2[nc] = sb[0] + sb[1] + sb[2] + sb[3];
    }
}

// ---------------- Kernel 2: per-channel logits + argmax ----------------
// One block (1 wave) per channel c. Threads (g = t&31, half = t>>5) split the
// n-sum in two; shfl combines. Thread 0 does the 32-way first-occurrence argmax.
__global__ __launch_bounds__(64) void k_logits(const float* __restrict__ s1,
                                               const float* __restrict__ s2,
                                               const float* __restrict__ fc_w,
                                               const float* __restrict__ fc_b,
                                               int* __restrict__ gidx) {
    const int c = blockIdx.x;
    const int t = threadIdx.x;
    const int g = t & 31, half = t >> 5;
    const float inv_hw  = 1.f / (float)HW_;
    const float inv_hw1 = 1.f / (float)(HW_ - 1);
    const float* wg = fc_w + g * (2 * N_);
    float acc = half ? 0.f : fc_b[g];
    const int n0 = half * 32;
    #pragma unroll 8
    for (int n = n0; n < n0 + 32; ++n) {
        const float v1 = s1[n * C_ + c];
        const float v2 = s2[n * C_ + c];
        const float m  = v1 * inv_hw;
        const float vr = (v2 - v1 * m) * inv_hw1;   // ddof=1
        acc += m * wg[n] + vr * wg[N_ + n];
    }
    acc += __shfl_down(acc, 32, 64);
    __shared__ float lg[G_];
    if (half == 0) lg[g] = acc;
    __syncthreads();
    if (t == 0) {
        float best = lg[0];
        int bi = 0;
        for (int g2 = 1; g2 < G_; ++g2) {
            const float v = lg[g2];
            if (v > best) { best = v; bi = g2; }
        }
        gidx[c] = bi;
    }
}

// ---------------- Kernel 3: per-n group stats -> fused scale/shift ----------------
// One block per n. Deterministic ascending-c accumulation (matches reference order).
__global__ __launch_bounds__(256) void k_group(const float* __restrict__ s1,
                                               const float* __restrict__ s2,
                                               const int* __restrict__ gidx,
                                               const float* __restrict__ weight,
                                               const float* __restrict__ bias,
                                               float* __restrict__ scale,
                                               float* __restrict__ shift) {
    const int n = blockIdx.x;
    const int c = threadIdx.x;
    __shared__ float r1[C_], r2[C_];
    __shared__ int   gi[C_];
    __shared__ float mg[G_], ig[G_];
    r1[c] = s1[n * C_ + c];
    r2[c] = s2[n * C_ + c];
    gi[c] = gidx[c];
    __syncthreads();
    if (c < G_) {
        float A = 0.f, B = 0.f;
        int k = 0;
        for (int cc = 0; cc < C_; ++cc) {
            if (gi[cc] == c) { A += r1[cc]; B += r2[cc]; ++k; }
        }
        const float cf = (float)k * (float)HW_;
        const float m  = A / fmaxf(cf, 1.f);
        const float vr = (B - A * m) / fmaxf(cf - 1.f, 1.f);
        mg[c] = m;
        ig[c] = rsqrtf(vr + EPS_);
    }
    __syncthreads();
    const int g = gi[c];
    const float sc = ig[g] * weight[c];
    scale[n * C_ + c] = sc;
    shift[n * C_ + c] = bias[c] - mg[g] * sc;
}

// ---------------- Kernel 4: elementwise normalize ----------------
__global__ __launch_bounds__(256) void k_norm(const float* __restrict__ x,
                                              const float* __restrict__ scale,
                                              const float* __restrict__ shift,
                                              float* __restrict__ out) {
    const int nc = blockIdx.x;
    const float sc = scale[nc];
    const float sh = shift[nc];
    const float4* xp = reinterpret_cast<const float4*>(x + (size_t)nc * HW_);
    float4* op = reinterpret_cast<float4*>(out + (size_t)nc * HW_);
    constexpr int NV = HW_ / 4;
    for (int i = threadIdx.x; i < NV; i += 256) {
        float4 v = xp[i];
        v.x = v.x * sc + sh;
        v.y = v.y * sc + sh;
        v.z = v.z * sc + sh;
        v.w = v.w * sc + sh;
        op[i] = v;
    }
}

extern "C" void kernel_launch(void* const* d_in, const int* in_sizes, int n_in,
                              void* d_out, int out_size, void* d_ws, size_t ws_size,
                              hipStream_t stream) {
    const float* x      = (const float*)d_in[0];
    const float* fc_w   = (const float*)d_in[1];
    const float* fc_b   = (const float*)d_in[2];
    const float* weight = (const float*)d_in[3];
    const float* bias   = (const float*)d_in[4];
    float* out = (float*)d_out;

    float* ws    = (float*)d_ws;
    float* s1    = ws;
    float* s2    = ws + NC_;
    float* scale = ws + 2 * NC_;
    float* shift = ws + 3 * NC_;
    int*   gidx  = (int*)(ws + 4 * NC_);

    k_sums  <<<NC_, 256, 0, stream>>>(x, s1, s2);
    k_logits<<<C_,   64, 0, stream>>>(s1, s2, fc_w, fc_b, gidx);
    k_group <<<N_,  256, 0, stream>>>(s1, s2, gidx, weight, bias, scale, shift);
    k_norm  <<<NC_, 256, 0, stream>>>(x, scale, shift, out);
}

// Round 4
// 120.727 us; speedup vs baseline: 2.5002x; 1.1077x over previous
//
#include <hip/hip_runtime.h>

constexpr int N_  = 64;
constexpr int C_  = 256;
constexpr int HW_ = 56 * 56;        // 3136
constexpr int G_  = 32;
constexpr int NC_ = N_ * C_;        // 16384
constexpr float EPS_ = 1e-5f;

typedef float f32x4 __attribute__((ext_vector_type(4)));   // native vector: OK for nontemporal builtins

// ---------------- Kernel 1: per-(n,c) sum and sum-of-squares ----------------
// One block per (n,c) slice: 784 float4 = 3*256 + 16. Explicit 3-deep unroll
// for memory-level parallelism; threads 0-15 take the tail vector.
__global__ __launch_bounds__(256) void k_sums(const float* __restrict__ x,
                                              float* __restrict__ s1,
                                              float* __restrict__ s2) {
    const int nc = blockIdx.x;
    const int t = threadIdx.x;
    const f32x4* xp = reinterpret_cast<const f32x4*>(x + (size_t)nc * HW_);
    f32x4 v0 = xp[t];
    f32x4 v1 = xp[t + 256];
    f32x4 v2 = xp[t + 512];
    f32x4 v3;
    if (t < 16) v3 = xp[t + 768];
    float a = (v0.x + v0.y) + (v0.z + v0.w)
            + (v1.x + v1.y) + (v1.z + v1.w)
            + (v2.x + v2.y) + (v2.z + v2.w);
    float b = (v0.x*v0.x + v0.y*v0.y) + (v0.z*v0.z + v0.w*v0.w)
            + (v1.x*v1.x + v1.y*v1.y) + (v1.z*v1.z + v1.w*v1.w)
            + (v2.x*v2.x + v2.y*v2.y) + (v2.z*v2.z + v2.w*v2.w);
    if (t < 16) {
        a += (v3.x + v3.y) + (v3.z + v3.w);
        b += (v3.x*v3.x + v3.y*v3.y) + (v3.z*v3.z + v3.w*v3.w);
    }
    for (int off = 32; off; off >>= 1) {
        a += __shfl_down(a, off, 64);
        b += __shfl_down(b, off, 64);
    }
    __shared__ float sa[4], sb[4];
    const int wid = t >> 6, lane = t & 63;
    if (lane == 0) { sa[wid] = a; sb[wid] = b; }
    __syncthreads();
    if (t == 0) {
        s1[nc] = (sa[0] + sa[1]) + (sa[2] + sa[3]);
        s2[nc] = (sb[0] + sb[1]) + (sb[2] + sb[3]);
    }
}

// ---------------- Kernel 2: per-channel logits + argmax ----------------
__global__ __launch_bounds__(64) void k_logits(const float* __restrict__ s1,
                                               const float* __restrict__ s2,
                                               const float* __restrict__ fc_w,
                                               const float* __restrict__ fc_b,
                                               int* __restrict__ gidx) {
    const int c = blockIdx.x;
    const int t = threadIdx.x;
    const int g = t & 31, half = t >> 5;
    const float inv_hw  = 1.f / (float)HW_;
    const float inv_hw1 = 1.f / (float)(HW_ - 1);
    const float* wg = fc_w + g * (2 * N_);
    float acc = half ? 0.f : fc_b[g];
    const int n0 = half * 32;
    #pragma unroll 8
    for (int n = n0; n < n0 + 32; ++n) {
        const float v1 = s1[n * C_ + c];
        const float v2 = s2[n * C_ + c];
        const float m  = v1 * inv_hw;
        const float vr = (v2 - v1 * m) * inv_hw1;   // ddof=1
        acc += m * wg[n] + vr * wg[N_ + n];
    }
    acc += __shfl_down(acc, 32, 64);
    __shared__ float lg[G_];
    if (half == 0) lg[g] = acc;
    __syncthreads();
    if (t == 0) {
        float best = lg[0];
        int bi = 0;
        for (int g2 = 1; g2 < G_; ++g2) {
            const float v = lg[g2];
            if (v > best) { best = v; bi = g2; }
        }
        gidx[c] = bi;
    }
}

// ---------------- Kernel 3: per-n group stats -> fused scale/shift ----------------
__global__ __launch_bounds__(256) void k_group(const float* __restrict__ s1,
                                               const float* __restrict__ s2,
                                               const int* __restrict__ gidx,
                                               const float* __restrict__ weight,
                                               const float* __restrict__ bias,
                                               float* __restrict__ scale,
                                               float* __restrict__ shift) {
    const int n = blockIdx.x;
    const int c = threadIdx.x;
    __shared__ float r1[C_], r2[C_];
    __shared__ int   gi[C_];
    __shared__ float mg[G_], ig[G_];
    r1[c] = s1[n * C_ + c];
    r2[c] = s2[n * C_ + c];
    gi[c] = gidx[c];
    __syncthreads();
    if (c < G_) {
        float A = 0.f, B = 0.f;
        int k = 0;
        for (int cc = 0; cc < C_; ++cc) {
            if (gi[cc] == c) { A += r1[cc]; B += r2[cc]; ++k; }
        }
        const float cf = (float)k * (float)HW_;
        const float m  = A / fmaxf(cf, 1.f);
        const float vr = (B - A * m) / fmaxf(cf - 1.f, 1.f);
        mg[c] = m;
        ig[c] = rsqrtf(vr + EPS_);
    }
    __syncthreads();
    const int g = gi[c];
    const float sc = ig[g] * weight[c];
    scale[n * C_ + c] = sc;
    shift[n * C_ + c] = bias[c] - mg[g] * sc;
}

// ---------------- Kernel 4: elementwise normalize ----------------
// Non-temporal: out is never re-read; x is on its LAST read (early L3 evict
// frees room so the write stream doesn't kick out the unread tail of x).
__global__ __launch_bounds__(256) void k_norm(const float* __restrict__ x,
                                              const float* __restrict__ scale,
                                              const float* __restrict__ shift,
                                              float* __restrict__ out) {
    const int nc = blockIdx.x;
    const int t = threadIdx.x;
    const float sc = scale[nc];
    const float sh = shift[nc];
    const f32x4* xp = reinterpret_cast<const f32x4*>(x + (size_t)nc * HW_);
    f32x4* op = reinterpret_cast<f32x4*>(out + (size_t)nc * HW_);
    f32x4 v0 = __builtin_nontemporal_load(xp + t);
    f32x4 v1 = __builtin_nontemporal_load(xp + t + 256);
    f32x4 v2 = __builtin_nontemporal_load(xp + t + 512);
    f32x4 v3;
    if (t < 16) v3 = __builtin_nontemporal_load(xp + t + 768);
    v0 = v0 * sc + sh;
    v1 = v1 * sc + sh;
    v2 = v2 * sc + sh;
    __builtin_nontemporal_store(v0, op + t);
    __builtin_nontemporal_store(v1, op + t + 256);
    __builtin_nontemporal_store(v2, op + t + 512);
    if (t < 16) {
        v3 = v3 * sc + sh;
        __builtin_nontemporal_store(v3, op + t + 768);
    }
}

extern "C" void kernel_launch(void* const* d_in, const int* in_sizes, int n_in,
                              void* d_out, int out_size, void* d_ws, size_t ws_size,
                              hipStream_t stream) {
    const float* x      = (const float*)d_in[0];
    const float* fc_w   = (const float*)d_in[1];
    const float* fc_b   = (const float*)d_in[2];
    const float* weight = (const float*)d_in[3];
    const float* bias   = (const float*)d_in[4];
    float* out = (float*)d_out;

    float* ws    = (float*)d_ws;
    float* s1    = ws;
    float* s2    = ws + NC_;
    float* scale = ws + 2 * NC_;
    float* shift = ws + 3 * NC_;
    int*   gidx  = (int*)(ws + 4 * NC_);

    k_sums  <<<NC_, 256, 0, stream>>>(x, s1, s2);
    k_logits<<<C_,   64, 0, stream>>>(s1, s2, fc_w, fc_b, gidx);
    k_group <<<N_,  256, 0, stream>>>(s1, s2, gidx, weight, bias, scale, shift);
    k_norm  <<<NC_, 256, 0, stream>>>(x, scale, shift, out);
}

// Round 5
// 120.608 us; speedup vs baseline: 2.5027x; 1.0010x over previous
//
#include <hip/hip_runtime.h>

constexpr int N_  = 64;
constexpr int C_  = 256;
constexpr int HW_ = 56 * 56;        // 3136 floats per slice = 784 float4
constexpr int G_  = 32;
constexpr int NC_ = N_ * C_;        // 16384
constexpr float EPS_ = 1e-5f;

typedef float f32x4 __attribute__((ext_vector_type(4)));

// ---------------- Kernel 1: per-(n,c) sum & sumsq — one WAVE per slice ----------------
// 784 vectors/slice = 12 per lane + lanes 0-15 take one more. No LDS, no syncthreads.
__global__ __launch_bounds__(256) void k_sums(const float* __restrict__ x,
                                              float* __restrict__ s1,
                                              float* __restrict__ s2) {
    const int wave = threadIdx.x >> 6;
    const int lane = threadIdx.x & 63;
    const int nc = blockIdx.x * 4 + wave;
    const f32x4* xp = reinterpret_cast<const f32x4*>(x + (size_t)nc * HW_);
    f32x4 v[12];
    #pragma unroll
    for (int k = 0; k < 12; ++k) v[k] = xp[lane + k * 64];
    f32x4 vt;
    const bool tail = lane < 16;
    if (tail) vt = xp[768 + lane];
    float a = 0.f, b = 0.f;
    #pragma unroll
    for (int k = 0; k < 12; ++k) {
        a += (v[k].x + v[k].y) + (v[k].z + v[k].w);
        b += (v[k].x * v[k].x + v[k].y * v[k].y) + (v[k].z * v[k].z + v[k].w * v[k].w);
    }
    if (tail) {
        a += (vt.x + vt.y) + (vt.z + vt.w);
        b += (vt.x * vt.x + vt.y * vt.y) + (vt.z * vt.z + vt.w * vt.w);
    }
    #pragma unroll
    for (int off = 32; off; off >>= 1) {
        a += __shfl_down(a, off, 64);
        b += __shfl_down(b, off, 64);
    }
    if (lane == 0) { s1[nc] = a; s2[nc] = b; }
}

// ---------------- Kernel 2: per-channel logits + argmax ----------------
__global__ __launch_bounds__(64) void k_logits(const float* __restrict__ s1,
                                               const float* __restrict__ s2,
                                               const float* __restrict__ fc_w,
                                               const float* __restrict__ fc_b,
                                               int* __restrict__ gidx) {
    const int c = blockIdx.x;
    const int t = threadIdx.x;
    const int g = t & 31, half = t >> 5;
    const float inv_hw  = 1.f / (float)HW_;
    const float inv_hw1 = 1.f / (float)(HW_ - 1);
    const float* wg = fc_w + g * (2 * N_);
    float acc = half ? 0.f : fc_b[g];
    const int n0 = half * 32;
    #pragma unroll 8
    for (int n = n0; n < n0 + 32; ++n) {
        const float v1 = s1[n * C_ + c];
        const float v2 = s2[n * C_ + c];
        const float m  = v1 * inv_hw;
        const float vr = (v2 - v1 * m) * inv_hw1;   // ddof=1
        acc += m * wg[n] + vr * wg[N_ + n];
    }
    acc += __shfl_down(acc, 32, 64);
    __shared__ float lg[G_];
    if (half == 0) lg[g] = acc;
    __syncthreads();
    if (t == 0) {
        float best = lg[0];
        int bi = 0;
        for (int g2 = 1; g2 < G_; ++g2) {
            const float v = lg[g2];
            if (v > best) { best = v; bi = g2; }
        }
        gidx[c] = bi;
    }
}

// ---------------- Kernel 3: per-n group stats -> fused scale/shift ----------------
__global__ __launch_bounds__(256) void k_group(const float* __restrict__ s1,
                                               const float* __restrict__ s2,
                                               const int* __restrict__ gidx,
                                               const float* __restrict__ weight,
                                               const float* __restrict__ bias,
                                               float* __restrict__ scale,
                                               float* __restrict__ shift) {
    const int n = blockIdx.x;
    const int c = threadIdx.x;
    __shared__ float r1[C_], r2[C_];
    __shared__ int   gi[C_];
    __shared__ float mg[G_], ig[G_];
    r1[c] = s1[n * C_ + c];
    r2[c] = s2[n * C_ + c];
    gi[c] = gidx[c];
    __syncthreads();
    if (c < G_) {
        float A = 0.f, B = 0.f;
        int k = 0;
        for (int cc = 0; cc < C_; ++cc) {
            if (gi[cc] == c) { A += r1[cc]; B += r2[cc]; ++k; }
        }
        const float cf = (float)k * (float)HW_;
        const float m  = A / fmaxf(cf, 1.f);
        const float vr = (B - A * m) / fmaxf(cf - 1.f, 1.f);
        mg[c] = m;
        ig[c] = rsqrtf(vr + EPS_);
    }
    __syncthreads();
    const int g = gi[c];
    const float sc = ig[g] * weight[c];
    scale[n * C_ + c] = sc;
    shift[n * C_ + c] = bias[c] - mg[g] * sc;
}

// ---------------- Kernel 4: normalize — one WAVE per slice ----------------
// Regular loads for x (keep it L3-resident for the NEXT replay's k_sums);
// non-temporal stores for out (never re-read, don't pollute L3).
__global__ __launch_bounds__(256) void k_norm(const float* __restrict__ x,
                                              const float* __restrict__ scale,
                                              const float* __restrict__ shift,
                                              float* __restrict__ out) {
    const int wave = threadIdx.x >> 6;
    const int lane = threadIdx.x & 63;
    const int nc = blockIdx.x * 4 + wave;
    const float sc = scale[nc];
    const float sh = shift[nc];
    const f32x4* xp = reinterpret_cast<const f32x4*>(x + (size_t)nc * HW_);
    f32x4* op = reinterpret_cast<f32x4*>(out + (size_t)nc * HW_);
    f32x4 v[12];
    #pragma unroll
    for (int k = 0; k < 12; ++k) v[k] = xp[lane + k * 64];
    f32x4 vt;
    const bool tail = lane < 16;
    if (tail) vt = xp[768 + lane];
    #pragma unroll
    for (int k = 0; k < 12; ++k) {
        v[k] = v[k] * sc + sh;
        __builtin_nontemporal_store(v[k], op + lane + k * 64);
    }
    if (tail) {
        vt = vt * sc + sh;
        __builtin_nontemporal_store(vt, op + 768 + lane);
    }
}

extern "C" void kernel_launch(void* const* d_in, const int* in_sizes, int n_in,
                              void* d_out, int out_size, void* d_ws, size_t ws_size,
                              hipStream_t stream) {
    const float* x      = (const float*)d_in[0];
    const float* fc_w   = (const float*)d_in[1];
    const float* fc_b   = (const float*)d_in[2];
    const float* weight = (const float*)d_in[3];
    const float* bias   = (const float*)d_in[4];
    float* out = (float*)d_out;

    float* ws    = (float*)d_ws;
    float* s1    = ws;
    float* s2    = ws + NC_;
    float* scale = ws + 2 * NC_;
    float* shift = ws + 3 * NC_;
    int*   gidx  = (int*)(ws + 4 * NC_);

    k_sums  <<<NC_ / 4, 256, 0, stream>>>(x, s1, s2);
    k_logits<<<C_,       64, 0, stream>>>(s1, s2, fc_w, fc_b, gidx);
    k_group <<<N_,      256, 0, stream>>>(s1, s2, gidx, weight, bias, scale, shift);
    k_norm  <<<NC_ / 4, 256, 0, stream>>>(x, scale, shift, out);
}